// Round 2
// baseline (108.073 us; speedup 1.0000x reference)
//
#include <hip/hip_runtime.h>
#include <math.h>

// Problem constants
#define DMODEL 256
#define NSEQ   512
#define MSEQ   512
#define NHEAD  4
#define DHEAD  64

// ws layout (float offsets)
#define WS_Q      0            // [512][256]
#define WS_K      131072       // [512][256]
#define WS_V      262144       // [512][256]
#define WS_WPE    393216       // [512][256][4]  (n, d, h)
#define WS_SCORES 917504       // [4][512][512]
// total floats = 1966080 -> 7.5 MB

// ---------------------------------------------------------------------------
// Kernel A: q/k/v projections.  Y = X @ W^T + b   (fp32)
// grid = 3 * 64 blocks (matrix, 8-row block), 256 threads (thread = out col)
// ---------------------------------------------------------------------------
__global__ __launch_bounds__(256) void proj_qkv(
    const float* __restrict__ xq, const float* __restrict__ xk,
    const float* __restrict__ xv,
    const float* __restrict__ Wq, const float* __restrict__ bq,
    const float* __restrict__ Wk, const float* __restrict__ bk,
    const float* __restrict__ Wv, const float* __restrict__ bv,
    float* __restrict__ ws)
{
    int bid = blockIdx.x;
    int mat = bid >> 6;       // 0=q 1=k 2=v
    int rb  = bid & 63;       // 8-row block
    const float* X; const float* W; const float* b; float* Y;
    if (mat == 0)      { X = xq; W = Wq; b = bq; Y = ws + WS_Q; }
    else if (mat == 1) { X = xk; W = Wk; b = bk; Y = ws + WS_K; }
    else               { X = xv; W = Wv; b = bv; Y = ws + WS_V; }

    int c  = threadIdx.x;
    int r0 = rb * 8;
    float acc[8];
    float bias = b[c];
#pragma unroll
    for (int r = 0; r < 8; ++r) acc[r] = bias;

    const float4* Wrow = (const float4*)(W + (size_t)c * DMODEL);
    for (int d4 = 0; d4 < 64; ++d4) {
        float4 w = Wrow[d4];
#pragma unroll
        for (int r = 0; r < 8; ++r) {
            float4 x = ((const float4*)(X + (size_t)(r0 + r) * DMODEL))[d4];
            acc[r] += w.x * x.x + w.y * x.y + w.z * x.z + w.w * x.w;
        }
    }
#pragma unroll
    for (int r = 0; r < 8; ++r)
        Y[(size_t)(r0 + r) * DMODEL + c] = acc[r];
}

// ---------------------------------------------------------------------------
// Kernel B: W'[n][d][h] = sum_dh q[n][h*64+dh] * Wp[h*64+dh][d]
// grid = 256 blocks (2 n each), 256 threads (thread = d).
// ---------------------------------------------------------------------------
__global__ __launch_bounds__(256) void make_wpeff(
    const float* __restrict__ Wp, float* __restrict__ ws)
{
    const float* q   = ws + WS_Q;
    float*       wpe = ws + WS_WPE;
    int n0 = blockIdx.x * 2;
    int d  = threadIdx.x;

    const float* q0 = q + (size_t)n0 * DMODEL;
    const float* q1 = q0 + DMODEL;

    float acc0[4] = {0.f, 0.f, 0.f, 0.f};
    float acc1[4] = {0.f, 0.f, 0.f, 0.f};
#pragma unroll
    for (int h = 0; h < 4; ++h) {
        for (int dh = 0; dh < 64; ++dh) {
            int c = h * 64 + dh;
            float w = Wp[(size_t)c * DMODEL + d];
            acc0[h] += q0[c] * w;
            acc1[h] += q1[c] * w;
        }
    }
    *(float4*)&wpe[(size_t)n0 * 1024 + d * 4] =
        make_float4(acc0[0], acc0[1], acc0[2], acc0[3]);
    *(float4*)&wpe[(size_t)(n0 + 1) * 1024 + d * 4] =
        make_float4(acc1[0], acc1[1], acc1[2], acc1[3]);
}

// ---------------------------------------------------------------------------
// Kernel D: HBM-streaming kernel, instruction-coalesced version.
// scores_p[h][n][m] = sum_d input_p[n,m,d] * W'[n][d][h]
// grid = 1024 blocks (n, m-half of 256 rows), 256 threads (4 waves).
// Wave layout: 16 lanes per row, 4 rows per load instruction -> each global
// load instruction covers 4 x 256B contiguous segments. W' slice lives in
// registers (16 float4/lane); per-4-row reduce = 4-step shfl_xor over 16 lanes.
// ---------------------------------------------------------------------------
__global__ __launch_bounds__(256) void p_scores(
    const float* __restrict__ Xp, float* __restrict__ ws)
{
    const float* wpe    = ws + WS_WPE;
    float*       scores = ws + WS_SCORES;

    int bid  = blockIdx.x;
    int n    = bid >> 1;
    int m0   = (bid & 1) * 256;
    int tid  = threadIdx.x;
    int wv   = tid >> 6;
    int lane = tid & 63;
    int p    = lane & 15;         // d-slice within row
    int r3   = lane >> 4;         // row within group of 4

    // W' for this lane's d-slice: float4 x[j] covers d = 4p + 64j + c
    const float4* wp4 = (const float4*)(wpe + (size_t)n * 1024);
    float4 w[4][4];
#pragma unroll
    for (int j = 0; j < 4; ++j)
#pragma unroll
        for (int c = 0; c < 4; ++c)
            w[j][c] = wp4[4 * p + 64 * j + c];

    __shared__ float sm[4][256];

    const float4* base4 =
        (const float4*)Xp + ((size_t)n * MSEQ + m0 + wv * 64) * 64;

#pragma unroll 2
    for (int g = 0; g < 16; ++g) {
        int rbase = (g * 4 + r3) * 64 + p;
        float4 xv0 = base4[rbase + 0];
        float4 xv1 = base4[rbase + 16];
        float4 xv2 = base4[rbase + 32];
        float4 xv3 = base4[rbase + 48];

        float sh[4] = {0.f, 0.f, 0.f, 0.f};
        {
            const float4 xs[4] = {xv0, xv1, xv2, xv3};
#pragma unroll
            for (int j = 0; j < 4; ++j) {
                const float* xc = &xs[j].x;
#pragma unroll
                for (int c = 0; c < 4; ++c) {
                    const float* wf = &w[j][c].x;
#pragma unroll
                    for (int h = 0; h < 4; ++h)
                        sh[h] += xc[c] * wf[h];
                }
            }
        }
        // reduce over the 16 lanes of this row
#pragma unroll
        for (int off = 1; off < 16; off <<= 1) {
#pragma unroll
            for (int h = 0; h < 4; ++h)
                sh[h] += __shfl_xor(sh[h], off);
        }
        if (p == 0) {
            int ml = wv * 64 + g * 4 + r3;
            sm[0][ml] = sh[0];
            sm[1][ml] = sh[1];
            sm[2][ml] = sh[2];
            sm[3][ml] = sh[3];
        }
    }
    __syncthreads();

    size_t ob = (size_t)n * MSEQ + m0 + tid;
    scores[0 * 262144 + ob] = sm[0][tid];
    scores[1 * 262144 + ob] = sm[1][tid];
    scores[2 * 262144 + ob] = sm[2][tid];
    scores[3 * 262144 + ob] = sm[3][tid];
}

// ---------------------------------------------------------------------------
// Kernel C: scores = 0.125 * (scores_p + q.k + q.bp)
// grid = 256 blocks (64x64 tile), 256 threads.
// ---------------------------------------------------------------------------
__global__ __launch_bounds__(256) void qk_scores(
    const float* __restrict__ bp, float* __restrict__ ws)
{
    const float* q      = ws + WS_Q;
    const float* k      = ws + WS_K;
    float*       scores = ws + WS_SCORES;

    int bid = blockIdx.x;
    int h   = bid >> 6;
    int nt  = (bid >> 3) & 7;
    int mt  = bid & 7;
    int n0  = nt * 64, m0 = mt * 64;

    __shared__ float qs[64][76];
    __shared__ float ks[64][76];
    __shared__ float qb[64];

    int tid = threadIdx.x;
#pragma unroll
    for (int rep = 0; rep < 4; ++rep) {
        int idx = rep * 1024 + tid * 4;
        int row = idx >> 6, col = idx & 63;
        *(float4*)&qs[row][col] =
            *(const float4*)&q[(size_t)(n0 + row) * DMODEL + h * 64 + col];
        *(float4*)&ks[row][col] =
            *(const float4*)&k[(size_t)(m0 + row) * DMODEL + h * 64 + col];
    }
    __syncthreads();

    if (tid < 64) {
        float s = 0.f;
        for (int dh = 0; dh < 64; ++dh) s += qs[tid][dh] * bp[h * 64 + dh];
        qb[tid] = s;
    }
    __syncthreads();

    int tn = tid >> 4, tm = tid & 15;
    float acc[4][4] = {};
    for (int kk = 0; kk < 64; kk += 4) {
        float4 qf[4], kf[4];
#pragma unroll
        for (int i = 0; i < 4; ++i) {
            qf[i] = *(const float4*)&qs[tn * 4 + i][kk];
            kf[i] = *(const float4*)&ks[tm * 4 + i][kk];
        }
#pragma unroll
        for (int i = 0; i < 4; ++i)
#pragma unroll
            for (int j = 0; j < 4; ++j)
                acc[i][j] += qf[i].x * kf[j].x + qf[i].y * kf[j].y +
                             qf[i].z * kf[j].z + qf[i].w * kf[j].w;
    }

#pragma unroll
    for (int i = 0; i < 4; ++i) {
        int n = n0 + tn * 4 + i;
        float qbn = qb[tn * 4 + i];
        float4* pp = (float4*)&scores[(size_t)h * 262144 +
                                      (size_t)n * MSEQ + m0 + tm * 4];
        float4 sp = *pp;
        sp.x = 0.125f * (sp.x + acc[i][0] + qbn);
        sp.y = 0.125f * (sp.y + acc[i][1] + qbn);
        sp.z = 0.125f * (sp.z + acc[i][2] + qbn);
        sp.w = 0.125f * (sp.w + acc[i][3] + qbn);
        *pp = sp;
    }
}

// ---------------------------------------------------------------------------
// Kernel E: masked softmax over m + attn @ v, writes final output.
// grid = 256 blocks (h, 8-n group), 256 threads.
// pl padded to stride 9 + m = i*16+mq remap -> ~2-way LDS aliasing (was 16).
// ---------------------------------------------------------------------------
__global__ __launch_bounds__(256) void softmax_av(
    const unsigned char* __restrict__ mask,
    float* __restrict__ out, float* __restrict__ ws)
{
    const float* v      = ws + WS_V;
    const float* scores = ws + WS_SCORES;

    int bid = blockIdx.x;
    int h   = bid >> 6;
    int g   = bid & 63;
    int n0  = g * 8;

    __shared__ float  pl[MSEQ * 9];   // [m][j] stride 9, 18 KB
    __shared__ float4 red4[256];      // reduce scratch 4 KB
    __shared__ float  wred[4];

    int tid  = threadIdx.x;
    int lane = tid & 63, wv = tid >> 6;

    for (int j = 0; j < 8; ++j) {
        int n = n0 + j;
        const float* srow = scores + (size_t)h * 262144 + (size_t)n * MSEQ;
        float s0 = srow[tid];
        float s1 = srow[tid + 256];
        if (mask[tid])       s0 = -INFINITY;
        if (mask[tid + 256]) s1 = -INFINITY;

        float mx = fmaxf(s0, s1);
#pragma unroll
        for (int off = 32; off; off >>= 1) mx = fmaxf(mx, __shfl_xor(mx, off));
        if (lane == 0) wred[wv] = mx;
        __syncthreads();
        mx = fmaxf(fmaxf(wred[0], wred[1]), fmaxf(wred[2], wred[3]));

        float e0 = __expf(s0 - mx);
        float e1 = __expf(s1 - mx);
        float sm = e0 + e1;
#pragma unroll
        for (int off = 32; off; off >>= 1) sm += __shfl_xor(sm, off);
        __syncthreads();                 // wred consumed by all before rewrite
        if (lane == 0) wred[wv] = sm;
        __syncthreads();
        sm = wred[0] + wred[1] + wred[2] + wred[3];
        float rinv = 1.0f / sm;

        pl[(size_t)tid * 9 + j]         = e0 * rinv;
        pl[(size_t)(tid + 256) * 9 + j] = e1 * rinv;
        __syncthreads();
    }

    // AV: thread = (dhq 0..15, mq 0..15); m = i*16 + mq (consecutive rows
    // per instruction; pl stride 9 makes 9*mq a permutation mod 32).
    int dhq = tid & 15, mq = tid >> 4;
    float acc[8][4] = {};
    for (int i = 0; i < 32; ++i) {
        int m = i * 16 + mq;
        float4 vv = *(const float4*)&v[(size_t)m * DMODEL + h * 64 + dhq * 4];
        float4 pa = *(const float4*)&pl[(size_t)m * 9];
        float4 pb = *(const float4*)&pl[(size_t)m * 9 + 4];
#pragma unroll
        for (int j = 0; j < 4; ++j) {
            float pv = (&pa.x)[j];
            acc[j][0] += pv * vv.x; acc[j][1] += pv * vv.y;
            acc[j][2] += pv * vv.z; acc[j][3] += pv * vv.w;
        }
#pragma unroll
        for (int j = 0; j < 4; ++j) {
            float pv = (&pb.x)[j];
            acc[4 + j][0] += pv * vv.x; acc[4 + j][1] += pv * vv.y;
            acc[4 + j][2] += pv * vv.z; acc[4 + j][3] += pv * vv.w;
        }
    }

    // reduce the 16 mq partials per (n, dh) and store
    for (int j = 0; j < 8; ++j) {
        red4[mq * 16 + dhq] =
            make_float4(acc[j][0], acc[j][1], acc[j][2], acc[j][3]);
        __syncthreads();
        if (tid < 64) {
            int dq = tid >> 2, x = tid & 3;
            float s = 0.f;
#pragma unroll
            for (int qq = 0; qq < 16; ++qq)
                s += ((const float*)&red4[qq * 16 + dq])[x];
            out[(size_t)(n0 + j) * DMODEL + h * 64 + tid] = s;
        }
        __syncthreads();
    }
}

// ---------------------------------------------------------------------------
extern "C" void kernel_launch(void* const* d_in, const int* in_sizes, int n_in,
                              void* d_out, int out_size, void* d_ws,
                              size_t ws_size, hipStream_t stream)
{
    const float* xq = (const float*)d_in[0];
    const float* xk = (const float*)d_in[1];
    const float* xv = (const float*)d_in[2];
    const float* xp = (const float*)d_in[3];
    const unsigned char* mask = (const unsigned char*)d_in[4];
    const float* Wq = (const float*)d_in[5];
    const float* bq = (const float*)d_in[6];
    const float* Wk = (const float*)d_in[7];
    const float* bk = (const float*)d_in[8];
    const float* Wv = (const float*)d_in[9];
    const float* bv = (const float*)d_in[10];
    const float* Wp = (const float*)d_in[11];
    const float* bp = (const float*)d_in[12];
    float* out = (float*)d_out;
    float* ws  = (float*)d_ws;

    proj_qkv  <<<192,  256, 0, stream>>>(xq, xk, xv, Wq, bq, Wk, bk, Wv, bv, ws);
    make_wpeff<<<256,  256, 0, stream>>>(Wp, ws);
    p_scores  <<<1024, 256, 0, stream>>>(xp, ws);
    qk_scores <<<256,  256, 0, stream>>>(bp, ws);
    softmax_av<<<256,  256, 0, stream>>>(mask, out, ws);
}